// Round 8
// baseline (136.795 us; speedup 1.0000x reference)
//
#include <hip/hip_runtime.h>

// SharedGroupLinearLayer R10.
// R9 = session best (sgll ~41.6us, ties R4). Ledger: occupancy (R8,
// spill-confounded), store-merge (R7, spilled), grid shape (R6) -- all
// neutral-or-worse; every clean kernel pins at 2.8-3.3 TB/s ~= HALF of the
// 6.3-6.5 TB/s that fill/copy kernels reach. The untested invariant:
// x-loads request only 32B per 64B sector per instruction (16B fragments
// at 32B stride, lane(col,q) layout) -> 50% sector efficiency on all input
// traffic. R10 tests exactly that: loads become lane-linear contiguous
// (lane*16B, 4x 1KB per 4KB tile = the copy-kernel pattern) and the MFMA
// fragment layout is recovered via a per-wave 4KB LDS transpose with a
// 16B-slot XOR swizzle (slot^token: <=2-way bank aliasing = free, m136).
// Wave-internal, no barriers. Stores unchanged from R9 (already 64B-
// sector-complete). DEPTH-4 rotation, all static indexing (no scratch).
//
// out[n,o] = (X w1^T + b1) + att0 * (X (w0-w1)^T + (b0-b1)),
// att0 = sigmoid(l0-l1); emb folded into acc init: C0 = b + E·W^T.

#define NBLK 512    // x 4 waves x 8 tiles x 16 tokens = 262144
#define TPW  8      // tiles per wave
#define DEPTH 4     // register pipeline depth (tiles in flight)

typedef short bf16x8 __attribute__((ext_vector_type(8)));
typedef float f32x4  __attribute__((ext_vector_type(4)));

union B8 { bf16x8 v; unsigned u[4]; };

__device__ __forceinline__ unsigned pk2bf(float lo, float hi) {
    unsigned a = __float_as_uint(lo) + 0x8000u;
    unsigned b = __float_as_uint(hi) + 0x8000u;
    return __builtin_amdgcn_perm(b, a, 0x07060302u);
}

__device__ __forceinline__ void pack8(B8& d, float4 p, float4 q) {
    d.u[0] = pk2bf(p.x, p.y); d.u[1] = pk2bf(p.z, p.w);
    d.u[2] = pk2bf(q.x, q.y); d.u[3] = pk2bf(q.z, q.w);
}

__global__ __launch_bounds__(256, 3) void sgll_kernel(
    const float* __restrict__ x,    // (262144, 64)
    const float* __restrict__ emb,  // (16, 64)  row = token % 16
    const float* __restrict__ rw,   // (64, 2)
    const float* __restrict__ ws,   // (2, 64, 64) w_stack[t][o][d]
    const float* __restrict__ bs,   // (2, 64)
    float* __restrict__ out)        // (262144, 64)
{
    __shared__ bf16x8 sW1[8][64];   // [kt*4+ot][lane]  w1 A-frags (8KB)
    __shared__ bf16x8 sWd[8][64];   // w0-w1 A-frags               (8KB)
    __shared__ float  sIn[4][1024]; // per-wave 4KB transpose tile (16KB)

    const int tid  = threadIdx.x;
    const int lane = tid & 63;
    const int wv   = tid >> 6;
    const int col  = lane & 15;
    const int q    = lane >> 4;

    // ---- setup: stage W frags (waves split the 8 (kt,ot) combos) ----
    #pragma unroll
    for (int c = wv; c < 8; c += 4) {
        const int kt = c >> 2, ot = c & 3;
        const float* p0 = ws + (ot * 16 + col) * 64 + kt * 32 + q * 8;  // w0
        const float* p1 = p0 + 4096;                                    // w1
        float4 a0 = *(const float4*)p0, a1 = *(const float4*)(p0 + 4);
        float4 c0 = *(const float4*)p1, c1 = *(const float4*)(p1 + 4);
        B8 f1, fd;
        pack8(f1, c0, c1);
        fd.u[0] = pk2bf(a0.x - c0.x, a0.y - c0.y);
        fd.u[1] = pk2bf(a0.z - c0.z, a0.w - c0.w);
        fd.u[2] = pk2bf(a1.x - c1.x, a1.y - c1.y);
        fd.u[3] = pk2bf(a1.z - c1.z, a1.w - c1.w);
        sW1[c][lane] = f1.v;
        sWd[c][lane] = fd.v;
    }

    // ---- R frags (regs), duplicated across row parity:
    // A[m][k] = rw[k][m&1] -> C rows 4q+0 / 4q+1 = (l0, l1) on EVERY lane.
    B8 R0, R1;
    {
        const int c01 = col & 1;
        float v[8];
        #pragma unroll
        for (int j = 0; j < 8; ++j)
            v[j] = rw[(q * 8 + j) * 2 + c01];
        pack8(R0, make_float4(v[0], v[1], v[2], v[3]), make_float4(v[4], v[5], v[6], v[7]));
        #pragma unroll
        for (int j = 0; j < 8; ++j)
            v[j] = rw[(32 + q * 8 + j) * 2 + c01];
        pack8(R1, make_float4(v[0], v[1], v[2], v[3]), make_float4(v[4], v[5], v[6], v[7]));
    }

    // ---- E frags + bias combos (regs, per wave) ----
    B8 E0, E1;
    {
        const float* ep = emb + col * 64 + q * 8;
        pack8(E0, *(const float4*)ep, *(const float4*)(ep + 4));
        pack8(E1, *(const float4*)(ep + 32), *(const float4*)(ep + 36));
    }
    f32x4 bI1[4], bId[4];
    #pragma unroll
    for (int ot = 0; ot < 4; ++ot) {
        float4 b1 = *(const float4*)(bs + 64 + ot * 16 + q * 4);
        float4 b0 = *(const float4*)(bs + ot * 16 + q * 4);
        bI1[ot][0] = b1.x; bI1[ot][1] = b1.y; bI1[ot][2] = b1.z; bI1[ot][3] = b1.w;
        bId[ot][0] = b0.x - b1.x; bId[ot][1] = b0.y - b1.y;
        bId[ot][2] = b0.z - b1.z; bId[ot][3] = b0.w - b1.w;
    }

    __syncthreads();  // W frags ready

    // ---- LDS transpose addresses (float indices), XOR slot swizzle ----
    // 4KB tile = 16 token rows x 256B; 16B slot s of token t lives at
    // t*256 + (s^t)*16 bytes. Writes: lane holds slot (lane&15) of token
    // 4j+(lane>>4). Reads: lane (col,q) needs slots {2q,2q+1,8+2q,8+2q+1}
    // of token col (= MFMA B-frag floats q*8..+8 and 32+q*8..+8).
    float* const sI = &sIn[wv][0];
    int wAd[4], rAd[4];
    #pragma unroll
    for (int j = 0; j < 4; ++j) {
        const int tok = 4 * j + (lane >> 4);
        wAd[j] = tok * 64 + (((lane & 15) ^ tok) << 2);
        const int s = (j >> 1) * 8 + 2 * q + (j & 1);
        rAd[j] = col * 64 + ((s ^ col) << 2);
    }

    // ---- prologue: fill pipeline, lane-linear loads (4x contiguous 1KB) ----
    const long base = (long)(blockIdx.x * 4 + wv) * (TPW * 16);   // first token
    const float* const xb = x + base * 64;       // tile t at +t*1024 floats
    float4 buf[DEPTH][4];
    #pragma unroll
    for (int t = 0; t < DEPTH; ++t) {
        const float* p = xb + t * 1024 + lane * 4;
        buf[t][0] = *(const float4*)p;
        buf[t][1] = *(const float4*)(p + 256);
        buf[t][2] = *(const float4*)(p + 512);
        buf[t][3] = *(const float4*)(p + 768);
    }
    __builtin_amdgcn_sched_barrier(0);   // pin the burst before compute

    // ---- acc init via MFMA (overlaps prologue load latency) ----
    f32x4 I1[4], Id[4], Il;
    #pragma unroll
    for (int ot = 0; ot < 4; ++ot) {
        f32x4 a1 = bI1[ot], ad = bId[ot];
        a1 = __builtin_amdgcn_mfma_f32_16x16x32_bf16(sW1[ot][lane],     E0.v, a1, 0, 0, 0);
        a1 = __builtin_amdgcn_mfma_f32_16x16x32_bf16(sW1[4 + ot][lane], E1.v, a1, 0, 0, 0);
        ad = __builtin_amdgcn_mfma_f32_16x16x32_bf16(sWd[ot][lane],     E0.v, ad, 0, 0, 0);
        ad = __builtin_amdgcn_mfma_f32_16x16x32_bf16(sWd[4 + ot][lane], E1.v, ad, 0, 0, 0);
        I1[ot] = a1;
        Id[ot] = ad;
    }
    {
        f32x4 z = {0.f, 0.f, 0.f, 0.f};
        z = __builtin_amdgcn_mfma_f32_16x16x32_bf16(R0.v, E0.v, z, 0, 0, 0);
        z = __builtin_amdgcn_mfma_f32_16x16x32_bf16(R1.v, E1.v, z, 0, 0, 0);
        Il = z;
    }

    // ---- steady state: stage->LDS, refill slot, read frags, compute ----
    #pragma unroll
    for (int i = 0; i < TPW; ++i) {
        const int b = i & (DEPTH - 1);

        // stage tile i into the wave's LDS transpose tile
        #pragma unroll
        for (int j = 0; j < 4; ++j)
            *(float4*)(sI + wAd[j]) = buf[b][j];

        // refill the slot with tile i+DEPTH (keeps load queue full)
        if (i + DEPTH < TPW) {
            const float* p = xb + (i + DEPTH) * 1024 + lane * 4;
            buf[b][0] = *(const float4*)p;
            buf[b][1] = *(const float4*)(p + 256);
            buf[b][2] = *(const float4*)(p + 512);
            buf[b][3] = *(const float4*)(p + 768);
        }

        // read back in MFMA fragment layout (<=2-way bank alias = free)
        float4 r0 = *(const float4*)(sI + rAd[0]);
        float4 r1 = *(const float4*)(sI + rAd[1]);
        float4 r2 = *(const float4*)(sI + rAd[2]);
        float4 r3 = *(const float4*)(sI + rAd[3]);
        B8 X0, X1;
        pack8(X0, r0, r1);
        pack8(X1, r2, r3);

        f32x4 lac = Il;
        lac = __builtin_amdgcn_mfma_f32_16x16x32_bf16(R0.v, X0.v, lac, 0, 0, 0);
        lac = __builtin_amdgcn_mfma_f32_16x16x32_bf16(R1.v, X1.v, lac, 0, 0, 0);
        // rows 4q+0 / 4q+1 hold (l0, l1) on every lane -> no shuffle
        const float att = 1.0f / (1.0f + __expf(lac[1] - lac[0]));

        const long rowoff = (base + (long)i * 16 + col) * 64;
        #pragma unroll
        for (int ot = 0; ot < 4; ++ot) {
            f32x4 y = I1[ot];
            y = __builtin_amdgcn_mfma_f32_16x16x32_bf16(sW1[ot][lane],     X0.v, y, 0, 0, 0);
            y = __builtin_amdgcn_mfma_f32_16x16x32_bf16(sW1[4 + ot][lane], X1.v, y, 0, 0, 0);
            f32x4 d = Id[ot];
            d = __builtin_amdgcn_mfma_f32_16x16x32_bf16(sWd[ot][lane],     X0.v, d, 0, 0, 0);
            d = __builtin_amdgcn_mfma_f32_16x16x32_bf16(sWd[4 + ot][lane], X1.v, d, 0, 0, 0);
            float4 o;
            o.x = fmaf(att, d[0], y[0]);
            o.y = fmaf(att, d[1], y[1]);
            o.z = fmaf(att, d[2], y[2]);
            o.w = fmaf(att, d[3], y[3]);
            *(float4*)(out + rowoff + ot * 16 + q * 4) = o;   // 64B/token, sector-complete
        }
    }
}

extern "C" void kernel_launch(void* const* d_in, const int* in_sizes, int n_in,
                              void* d_out, int out_size, void* d_ws, size_t ws_size,
                              hipStream_t stream) {
    const float* x   = (const float*)d_in[0];
    const float* emb = (const float*)d_in[1];
    const float* rw  = (const float*)d_in[2];
    const float* wsk = (const float*)d_in[3];
    const float* bs  = (const float*)d_in[4];
    float* out = (float*)d_out;
    sgll_kernel<<<NBLK, 256, 0, stream>>>(x, emb, rw, wsk, bs, out);
}

// Round 9
// 136.526 us; speedup vs baseline: 1.0020x; 1.0020x over previous
//
#include <hip/hip_runtime.h>

// SharedGroupLinearLayer R11.
// R10 post-mortem: lane-linear loads FIXED traffic (hbm 137->101MB, WRITE
// exactly ideal) but time REGRESSED 41.6->49.4us -> kernel is latency/
// concurrency-limited, not BW-limited; the per-step LDS hop added serial
// latency that outweighed the traffic win. Ledger: sector-eff x, occupancy
// x (R8: 55% occ same BW), store-merge x, grid shape x. The variable that
// tracks ALL results: fraction of wave lifetime with loads in flight
// (refill fraction): R5b 0.00->51us, R6 0.38->49.4, R9 0.50->41.6.
// R11 = R9 byte-identical, NBLK 256 / TPW 16: refill fraction 0.75, half
// the chip-wide pure-stall prologues. One variable (work per wave).
//
// out[n,o] = (X w1^T + b1) + att0 * (X (w0-w1)^T + (b0-b1)),
// att0 = sigmoid(l0-l1); emb folded into acc init: C0 = b + E·W^T.

#define NBLK 256    // x 4 waves x 16 tiles x 16 tokens = 262144
#define TPW  16     // tiles per wave
#define DEPTH 4     // register pipeline depth (tiles in flight)

typedef short bf16x8 __attribute__((ext_vector_type(8)));
typedef float f32x4  __attribute__((ext_vector_type(4)));

union B8 { bf16x8 v; unsigned u[4]; };

__device__ __forceinline__ unsigned pk2bf(float lo, float hi) {
    unsigned a = __float_as_uint(lo) + 0x8000u;
    unsigned b = __float_as_uint(hi) + 0x8000u;
    return __builtin_amdgcn_perm(b, a, 0x07060302u);
}

__device__ __forceinline__ void pack8(B8& d, float4 p, float4 q) {
    d.u[0] = pk2bf(p.x, p.y); d.u[1] = pk2bf(p.z, p.w);
    d.u[2] = pk2bf(q.x, q.y); d.u[3] = pk2bf(q.z, q.w);
}

__global__ __launch_bounds__(256, 3) void sgll_kernel(
    const float* __restrict__ x,    // (262144, 64)
    const float* __restrict__ emb,  // (16, 64)  row = token % 16
    const float* __restrict__ rw,   // (64, 2)
    const float* __restrict__ ws,   // (2, 64, 64) w_stack[t][o][d]
    const float* __restrict__ bs,   // (2, 64)
    float* __restrict__ out)        // (262144, 64)
{
    __shared__ bf16x8 sW1[8][64];   // [kt*4+ot][lane]  w1 A-frags
    __shared__ bf16x8 sWd[8][64];   // w0-w1 A-frags

    const int tid  = threadIdx.x;
    const int lane = tid & 63;
    const int wv   = tid >> 6;
    const int col  = lane & 15;
    const int q    = lane >> 4;

    // ---- setup: stage W frags (waves split the 8 (kt,ot) combos) ----
    #pragma unroll
    for (int c = wv; c < 8; c += 4) {
        const int kt = c >> 2, ot = c & 3;
        const float* p0 = ws + (ot * 16 + col) * 64 + kt * 32 + q * 8;  // w0
        const float* p1 = p0 + 4096;                                    // w1
        float4 a0 = *(const float4*)p0, a1 = *(const float4*)(p0 + 4);
        float4 c0 = *(const float4*)p1, c1 = *(const float4*)(p1 + 4);
        B8 f1, fd;
        pack8(f1, c0, c1);
        fd.u[0] = pk2bf(a0.x - c0.x, a0.y - c0.y);
        fd.u[1] = pk2bf(a0.z - c0.z, a0.w - c0.w);
        fd.u[2] = pk2bf(a1.x - c1.x, a1.y - c1.y);
        fd.u[3] = pk2bf(a1.z - c1.z, a1.w - c1.w);
        sW1[c][lane] = f1.v;
        sWd[c][lane] = fd.v;
    }

    // ---- R frags (regs), duplicated across row parity:
    // A[m][k] = rw[k][m&1] -> C rows 4q+0 / 4q+1 = (l0, l1) on EVERY lane,
    // so att needs no cross-lane broadcast (validated R5b/R6/R9).
    B8 R0, R1;
    {
        const int c01 = col & 1;
        float v[8];
        #pragma unroll
        for (int j = 0; j < 8; ++j)
            v[j] = rw[(q * 8 + j) * 2 + c01];
        pack8(R0, make_float4(v[0], v[1], v[2], v[3]), make_float4(v[4], v[5], v[6], v[7]));
        #pragma unroll
        for (int j = 0; j < 8; ++j)
            v[j] = rw[(32 + q * 8 + j) * 2 + c01];
        pack8(R1, make_float4(v[0], v[1], v[2], v[3]), make_float4(v[4], v[5], v[6], v[7]));
    }

    // ---- E frags + bias combos (regs, per wave) ----
    B8 E0, E1;
    {
        const float* ep = emb + col * 64 + q * 8;
        pack8(E0, *(const float4*)ep, *(const float4*)(ep + 4));
        pack8(E1, *(const float4*)(ep + 32), *(const float4*)(ep + 36));
    }
    f32x4 bI1[4], bId[4];
    #pragma unroll
    for (int ot = 0; ot < 4; ++ot) {
        float4 b1 = *(const float4*)(bs + 64 + ot * 16 + q * 4);
        float4 b0 = *(const float4*)(bs + ot * 16 + q * 4);
        bI1[ot][0] = b1.x; bI1[ot][1] = b1.y; bI1[ot][2] = b1.z; bI1[ot][3] = b1.w;
        bId[ot][0] = b0.x - b1.x; bId[ot][1] = b0.y - b1.y;
        bId[ot][2] = b0.z - b1.z; bId[ot][3] = b0.w - b1.w;
    }

    __syncthreads();  // W frags ready

    // ---- prologue: fill the pipeline (DEPTH tiles = 16 dwordx4 in flight) ----
    const long base = (long)(blockIdx.x * 4 + wv) * (TPW * 16);   // first token
    float4 buf[DEPTH][4];
    #pragma unroll
    for (int t = 0; t < DEPTH; ++t) {
        const float* p = x + (base + (long)t * 16 + col) * 64 + q * 8;
        buf[t][0] = *(const float4*)p;        buf[t][1] = *(const float4*)(p + 4);
        buf[t][2] = *(const float4*)(p + 32); buf[t][3] = *(const float4*)(p + 36);
    }
    __builtin_amdgcn_sched_barrier(0);   // pin the burst before compute

    // ---- acc init via MFMA (overlaps prologue load latency) ----
    f32x4 I1[4], Id[4], Il;
    #pragma unroll
    for (int ot = 0; ot < 4; ++ot) {
        f32x4 a1 = bI1[ot], ad = bId[ot];
        a1 = __builtin_amdgcn_mfma_f32_16x16x32_bf16(sW1[ot][lane],     E0.v, a1, 0, 0, 0);
        a1 = __builtin_amdgcn_mfma_f32_16x16x32_bf16(sW1[4 + ot][lane], E1.v, a1, 0, 0, 0);
        ad = __builtin_amdgcn_mfma_f32_16x16x32_bf16(sWd[ot][lane],     E0.v, ad, 0, 0, 0);
        ad = __builtin_amdgcn_mfma_f32_16x16x32_bf16(sWd[4 + ot][lane], E1.v, ad, 0, 0, 0);
        I1[ot] = a1;
        Id[ot] = ad;
    }
    {
        f32x4 z = {0.f, 0.f, 0.f, 0.f};
        z = __builtin_amdgcn_mfma_f32_16x16x32_bf16(R0.v, E0.v, z, 0, 0, 0);
        z = __builtin_amdgcn_mfma_f32_16x16x32_bf16(R1.v, E1.v, z, 0, 0, 0);
        Il = z;
    }

    // ---- steady state: consume tile i, refill slot with tile i+DEPTH ----
    #pragma unroll
    for (int i = 0; i < TPW; ++i) {
        const int b = i & (DEPTH - 1);

        B8 X0, X1;
        pack8(X0, buf[b][0], buf[b][1]);
        pack8(X1, buf[b][2], buf[b][3]);

        // refill the slot immediately after the consume reads (keeps queue full)
        if (i + DEPTH < TPW) {
            const float* p = x + (base + (long)(i + DEPTH) * 16 + col) * 64 + q * 8;
            buf[b][0] = *(const float4*)p;        buf[b][1] = *(const float4*)(p + 4);
            buf[b][2] = *(const float4*)(p + 32); buf[b][3] = *(const float4*)(p + 36);
        }

        f32x4 lac = Il;
        lac = __builtin_amdgcn_mfma_f32_16x16x32_bf16(R0.v, X0.v, lac, 0, 0, 0);
        lac = __builtin_amdgcn_mfma_f32_16x16x32_bf16(R1.v, X1.v, lac, 0, 0, 0);
        // rows 4q+0 / 4q+1 hold (l0, l1) on every lane -> no shuffle
        const float att = 1.0f / (1.0f + __expf(lac[1] - lac[0]));

        const long rowoff = (base + (long)i * 16 + col) * 64;
        #pragma unroll
        for (int ot = 0; ot < 4; ++ot) {
            f32x4 y = I1[ot];
            y = __builtin_amdgcn_mfma_f32_16x16x32_bf16(sW1[ot][lane],     X0.v, y, 0, 0, 0);
            y = __builtin_amdgcn_mfma_f32_16x16x32_bf16(sW1[4 + ot][lane], X1.v, y, 0, 0, 0);
            f32x4 d = Id[ot];
            d = __builtin_amdgcn_mfma_f32_16x16x32_bf16(sWd[ot][lane],     X0.v, d, 0, 0, 0);
            d = __builtin_amdgcn_mfma_f32_16x16x32_bf16(sWd[4 + ot][lane], X1.v, d, 0, 0, 0);
            float4 o;
            o.x = fmaf(att, d[0], y[0]);
            o.y = fmaf(att, d[1], y[1]);
            o.z = fmaf(att, d[2], y[2]);
            o.w = fmaf(att, d[3], y[3]);
            *(float4*)(out + rowoff + ot * 16 + q * 4) = o;   // 16B coalesced
        }
    }
}

extern "C" void kernel_launch(void* const* d_in, const int* in_sizes, int n_in,
                              void* d_out, int out_size, void* d_ws, size_t ws_size,
                              hipStream_t stream) {
    const float* x   = (const float*)d_in[0];
    const float* emb = (const float*)d_in[1];
    const float* rw  = (const float*)d_in[2];
    const float* wsk = (const float*)d_in[3];
    const float* bs  = (const float*)d_in[4];
    float* out = (float*)d_out;
    sgll_kernel<<<NBLK, 256, 0, stream>>>(x, emb, rw, wsk, bs, out);
}

// Round 10
// 136.221 us; speedup vs baseline: 1.0042x; 1.0022x over previous
//
#include <hip/hip_runtime.h>

// SharedGroupLinearLayer R12 — global_load_lds DMA pipeline (T3/T4-lite).
// R11 post-mortem: TPW16@1blk/CU -> 47us, 8% occ. Session invariant:
// per-CU delivered BW pinned at 10-13 GB/s/CU across 4-18 waves/CU and
// every schedule/store/sector variant -> per-CU cap on the VGPR-return
// load path. R12 bypasses it: x staged by global_load_lds DMA (LDS-direct,
// no VGPR return), DEPTH-4 ring, counted inline-asm vmcnt waits (m135:
// loads drain in order; never 0 mid-loop). Consume = inline-asm
// ds_read_b128 (hides LDS-DMA alias from the waitcnt pass, which would
// otherwise insert vmcnt(0) per step) + lgkmcnt(0) + sched_barrier(0)
// (rule 18). Stores deferred to a wave-end burst so vmcnt counts loads
// only (sound counted waits). DMA dest is linear (HW), so transpose via
// pre-swizzled GLOBAL source (16B-slot XOR within 256B token rows, m173)
// + matching XOR on ds_read (<=2-way bank alias = free).
//
// out[n,o] = (X w1^T + b1) + att0 * (X (w0-w1)^T + (b0-b1)),
// att0 = sigmoid(l0-l1); emb folded into acc init: C0 = b + E·W^T.

#define NBLK 512    // x 4 waves x 8 tiles x 16 tokens = 262144
#define TPW  8      // tiles per wave
#define DEPTH 4     // DMA ring depth (tiles in flight)

typedef short bf16x8 __attribute__((ext_vector_type(8)));
typedef float f32x4  __attribute__((ext_vector_type(4)));

union B8 { bf16x8 v; unsigned u[4]; };

__device__ __forceinline__ unsigned pk2bf(float lo, float hi) {
    unsigned a = __float_as_uint(lo) + 0x8000u;
    unsigned b = __float_as_uint(hi) + 0x8000u;
    return __builtin_amdgcn_perm(b, a, 0x07060302u);
}

__device__ __forceinline__ void pack8(B8& d, float4 p, float4 q) {
    d.u[0] = pk2bf(p.x, p.y); d.u[1] = pk2bf(p.z, p.w);
    d.u[2] = pk2bf(q.x, q.y); d.u[3] = pk2bf(q.z, q.w);
}

__device__ __forceinline__ void pack8v(B8& d, f32x4 p, f32x4 r) {
    d.u[0] = pk2bf(p[0], p[1]); d.u[1] = pk2bf(p[2], p[3]);
    d.u[2] = pk2bf(r[0], r[1]); d.u[3] = pk2bf(r[2], r[3]);
}

__global__ __launch_bounds__(256, 2) void sgll_kernel(
    const float* __restrict__ x,    // (262144, 64)
    const float* __restrict__ emb,  // (16, 64)  row = token % 16
    const float* __restrict__ rw,   // (64, 2)
    const float* __restrict__ ws,   // (2, 64, 64) w_stack[t][o][d]
    const float* __restrict__ bs,   // (2, 64)
    float* __restrict__ out)        // (262144, 64)
{
    __shared__ bf16x8 sW1[8][64];      // w1 A-frags   (8KB)
    __shared__ bf16x8 sWd[8][64];      // w0-w1 frags  (8KB)
    __shared__ float  sX[4][DEPTH * 1024];  // per-wave DMA rings (64KB)

    const int tid  = threadIdx.x;
    const int lane = tid & 63;
    const int wv   = tid >> 6;
    const int col  = lane & 15;
    const int q    = lane >> 4;

    // ---- setup: stage W frags (waves split the 8 (kt,ot) combos) ----
    #pragma unroll
    for (int c = wv; c < 8; c += 4) {
        const int kt = c >> 2, ot = c & 3;
        const float* p0 = ws + (ot * 16 + col) * 64 + kt * 32 + q * 8;  // w0
        const float* p1 = p0 + 4096;                                    // w1
        float4 a0 = *(const float4*)p0, a1 = *(const float4*)(p0 + 4);
        float4 c0 = *(const float4*)p1, c1 = *(const float4*)(p1 + 4);
        B8 f1, fd;
        pack8(f1, c0, c1);
        fd.u[0] = pk2bf(a0.x - c0.x, a0.y - c0.y);
        fd.u[1] = pk2bf(a0.z - c0.z, a0.w - c0.w);
        fd.u[2] = pk2bf(a1.x - c1.x, a1.y - c1.y);
        fd.u[3] = pk2bf(a1.z - c1.z, a1.w - c1.w);
        sW1[c][lane] = f1.v;
        sWd[c][lane] = fd.v;
    }

    // ---- R frags (regs), parity-duplicated (att valid on all lanes) ----
    B8 R0, R1;
    {
        const int c01 = col & 1;
        float v[8];
        #pragma unroll
        for (int j = 0; j < 8; ++j)
            v[j] = rw[(q * 8 + j) * 2 + c01];
        pack8(R0, make_float4(v[0], v[1], v[2], v[3]), make_float4(v[4], v[5], v[6], v[7]));
        #pragma unroll
        for (int j = 0; j < 8; ++j)
            v[j] = rw[(32 + q * 8 + j) * 2 + c01];
        pack8(R1, make_float4(v[0], v[1], v[2], v[3]), make_float4(v[4], v[5], v[6], v[7]));
    }

    // ---- E frags + bias combos ----
    B8 E0, E1;
    {
        const float* ep = emb + col * 64 + q * 8;
        pack8(E0, *(const float4*)ep, *(const float4*)(ep + 4));
        pack8(E1, *(const float4*)(ep + 32), *(const float4*)(ep + 36));
    }
    f32x4 bI1[4], bId[4];
    #pragma unroll
    for (int ot = 0; ot < 4; ++ot) {
        float4 b1 = *(const float4*)(bs + 64 + ot * 16 + q * 4);
        float4 b0 = *(const float4*)(bs + ot * 16 + q * 4);
        bI1[ot][0] = b1.x; bI1[ot][1] = b1.y; bI1[ot][2] = b1.z; bI1[ot][3] = b1.w;
        bId[ot][0] = b0.x - b1.x; bId[ot][1] = b0.y - b1.y;
        bId[ot][2] = b0.z - b1.z; bId[ot][3] = b0.w - b1.w;
    }

    __syncthreads();  // W frags ready (also drains setup loads)

    const int w = blockIdx.x * 4 + wv;
    const long base = (long)w * (TPW * 16);        // first token
    const float* const xb = x + base * 64;
    float* const ring = &sX[wv][0];

    // ds_read addresses: LDS slot s' of token t holds global slot s'^t.
    // To read global slot s of token col: addr = col*256 + ((s^col)<<4).
    const unsigned ldsb = (unsigned)(uintptr_t)ring;
    const unsigned C0 = ldsb + col * 256 + (((2 * q + 0) ^ col) << 4);
    const unsigned C1 = ldsb + col * 256 + (((2 * q + 1) ^ col) << 4);
    const unsigned C2 = ldsb + col * 256 + (((8 + 2 * q + 0) ^ col) << 4);
    const unsigned C3 = ldsb + col * 256 + (((8 + 2 * q + 1) ^ col) << 4);

    // DMA one 4KB tile into ring slot: 4 instrs, LDS linear (lane*16),
    // global source pre-swizzled (slot s_lin reads global slot s_lin^t).
    auto dma = [&](int T, int slot) {
        #pragma unroll
        for (int k = 0; k < 4; ++k) {
            const int tk = k * 4 + q;                       // token in tile
            const float* g = xb + T * 1024 + tk * 64 + ((col ^ tk) << 2);
            __builtin_amdgcn_global_load_lds(g, ring + slot * 1024 + k * 256, 16, 0, 0);
        }
    };

    // ---- prologue: fill the DMA ring ----
    #pragma unroll
    for (int t = 0; t < DEPTH; ++t) dma(t, t);

    // ---- acc init via MFMA (overlaps DMA latency) ----
    f32x4 I1[4], Id[4], Il;
    #pragma unroll
    for (int ot = 0; ot < 4; ++ot) {
        f32x4 a1 = bI1[ot], ad = bId[ot];
        a1 = __builtin_amdgcn_mfma_f32_16x16x32_bf16(sW1[ot][lane],     E0.v, a1, 0, 0, 0);
        a1 = __builtin_amdgcn_mfma_f32_16x16x32_bf16(sW1[4 + ot][lane], E1.v, a1, 0, 0, 0);
        ad = __builtin_amdgcn_mfma_f32_16x16x32_bf16(sWd[ot][lane],     E0.v, ad, 0, 0, 0);
        ad = __builtin_amdgcn_mfma_f32_16x16x32_bf16(sWd[4 + ot][lane], E1.v, ad, 0, 0, 0);
        I1[ot] = a1;
        Id[ot] = ad;
    }
    {
        f32x4 z = {0.f, 0.f, 0.f, 0.f};
        z = __builtin_amdgcn_mfma_f32_16x16x32_bf16(R0.v, E0.v, z, 0, 0, 0);
        z = __builtin_amdgcn_mfma_f32_16x16x32_bf16(R1.v, E1.v, z, 0, 0, 0);
        Il = z;
    }

    f32x4 outs[TPW][4];   // deferred outputs (static-indexed under unroll)

    // ---- steady state: counted vmcnt -> asm ds_read -> refill DMA -> MFMA ----
    #pragma unroll
    for (int i = 0; i < TPW; ++i) {
        // wait for tile i's 4 DMAs (oldest); allow younger tiles in flight.
        if (i <= 4)      asm volatile("s_waitcnt vmcnt(12)");
        else if (i == 5) asm volatile("s_waitcnt vmcnt(8)");
        else if (i == 6) asm volatile("s_waitcnt vmcnt(4)");
        else             asm volatile("s_waitcnt vmcnt(0)");

        f32x4 r0, r1, r2, r3;
        asm volatile("ds_read_b128 %0, %1 offset:%c2" : "=v"(r0) : "v"(C0), "i"((i & 3) * 4096));
        asm volatile("ds_read_b128 %0, %1 offset:%c2" : "=v"(r1) : "v"(C1), "i"((i & 3) * 4096));
        asm volatile("ds_read_b128 %0, %1 offset:%c2" : "=v"(r2) : "v"(C2), "i"((i & 3) * 4096));
        asm volatile("ds_read_b128 %0, %1 offset:%c2" : "=v"(r3) : "v"(C3), "i"((i & 3) * 4096));
        asm volatile("s_waitcnt lgkmcnt(0)");
        __builtin_amdgcn_sched_barrier(0);     // rule 18: pin consumers after wait

        // slot free -> refill (issue overlaps the MFMA section below)
        if (i + DEPTH < TPW) dma(i + DEPTH, i & 3);

        B8 X0, X1;
        pack8v(X0, r0, r1);
        pack8v(X1, r2, r3);

        f32x4 lac = Il;
        lac = __builtin_amdgcn_mfma_f32_16x16x32_bf16(R0.v, X0.v, lac, 0, 0, 0);
        lac = __builtin_amdgcn_mfma_f32_16x16x32_bf16(R1.v, X1.v, lac, 0, 0, 0);
        const float att = 1.0f / (1.0f + __expf(lac[1] - lac[0]));

        #pragma unroll
        for (int ot = 0; ot < 4; ++ot) {
            f32x4 y = I1[ot];
            y = __builtin_amdgcn_mfma_f32_16x16x32_bf16(sW1[ot][lane],     X0.v, y, 0, 0, 0);
            y = __builtin_amdgcn_mfma_f32_16x16x32_bf16(sW1[4 + ot][lane], X1.v, y, 0, 0, 0);
            f32x4 d = Id[ot];
            d = __builtin_amdgcn_mfma_f32_16x16x32_bf16(sWd[ot][lane],     X0.v, d, 0, 0, 0);
            d = __builtin_amdgcn_mfma_f32_16x16x32_bf16(sWd[4 + ot][lane], X1.v, d, 0, 0, 0);
            f32x4 o;
            o[0] = fmaf(att, d[0], y[0]);
            o[1] = fmaf(att, d[1], y[1]);
            o[2] = fmaf(att, d[2], y[2]);
            o[3] = fmaf(att, d[3], y[3]);
            outs[i][ot] = o;
        }
    }

    // ---- epilogue: store burst (vmcnt now free of load traffic) ----
    #pragma unroll
    for (int i = 0; i < TPW; ++i) {
        const long rowoff = (base + (long)i * 16 + col) * 64;
        #pragma unroll
        for (int ot = 0; ot < 4; ++ot)
            *(f32x4*)(out + rowoff + ot * 16 + q * 4) = outs[i][ot];
    }
}

extern "C" void kernel_launch(void* const* d_in, const int* in_sizes, int n_in,
                              void* d_out, int out_size, void* d_ws, size_t ws_size,
                              hipStream_t stream) {
    const float* x   = (const float*)d_in[0];
    const float* emb = (const float*)d_in[1];
    const float* rw  = (const float*)d_in[2];
    const float* wsk = (const float*)d_in[3];
    const float* bs  = (const float*)d_in[4];
    float* out = (float*)d_out;
    sgll_kernel<<<NBLK, 256, 0, stream>>>(x, emb, rw, wsk, bs, out);
}